// Round 16
// baseline (290.301 us; speedup 1.0000x reference)
//
#include <hip/hip_runtime.h>
#include <math.h>

#define Bsz 512
#define TT 8
#define Dn 2048
#define DIN 512
#define Hh 4
#define Pn 512
#define DOUT 512
#define BD (Bsz*Dn)

typedef __attribute__((ext_vector_type(8))) short s16x8;
typedef __attribute__((ext_vector_type(4))) float f32x4;
typedef __attribute__((ext_vector_type(4))) unsigned short u16x4;

__device__ __forceinline__ unsigned short f2bf(float f) {
  unsigned int u = __float_as_uint(f);
  unsigned int r = (u + 0x7fffu + ((u >> 16) & 1u)) >> 16;
  return (unsigned short)r;
}
__device__ __forceinline__ float bf2f(unsigned short h) {
  return __uint_as_float(((unsigned int)h) << 16);
}
__device__ __forceinline__ void split2(float x, unsigned short& h, unsigned short& l) {
  h = f2bf(x);
  float r = x - bf2f(h);
  l = f2bf(r);
}

// async global->LDS, 16B per lane, LDS dest = wave-uniform base + lane*16
#define GLOAD16(g, l) __builtin_amdgcn_global_load_lds( \
    (const __attribute__((address_space(1))) unsigned int*)(g), \
    (__attribute__((address_space(3))) unsigned int*)(l), 16, 0, 0)

// ---------------- MFMA GEMM core (r16: ring-4 + vmcnt(8)) --------------------
// 64x64 block tile, 512 threads = 4 quadrant pairs: wave w -> quadrant qw=w&3
// (32x32), K-half g=w>>2 (kg window within each BK=64 stage).
// ONE shared 32KB stage per iter, ring-4 (128KB LDS):
//   iter i: s_waitcnt vmcnt(8)   [stage(i) retired; stages i+1,i+2 fly]
//           s_barrier; STAGE(slot (i+3)&3, i+3); 8 ds_read + 12 MFMA on i&3.
// r15's ring-3/vmcnt(4) gave stage(i) only ~1 iter of flight -> HBM latency
// still partially serialized each iter (+5us only). Two stages in flight
// gives ~2-3 iters (~600-1000cy) of flight, covering the miss latency.
// Reduction: K-half 1 dumps acc (pad-17), K-half 0 adds and owns epilogue.
__device__ __forceinline__ void gemm_core(
    const unsigned short* __restrict__ Ah, const unsigned short* __restrict__ Al,
    const unsigned short* __restrict__ BTh, const unsigned short* __restrict__ BTl,
    int K, long arow0, long brow0,
    unsigned short* LDS, f32x4 acc[2][2], int g, int qw)
{
  const int tid = threadIdx.x;
  const int lane = tid & 63;
  const int lh = lane >> 4, sc = lane & 15;
  // staging: waves 0-3 stage A rows qw*16..+16, waves 4-7 stage B rows qw*16..+16
  const unsigned short* Xh = g ? BTh : Ah;
  const unsigned short* Xl = g ? BTl : Al;
  const long row0 = g ? brow0 : arow0;
  const int bofs = g ? 8192 : 0;
  const unsigned short* gsrc[4];
  int ldst[4];
#pragma unroll
  for (int t = 0; t < 4; ++t) {
    int rb = qw * 16 + t * 4;
    int row = rb + lh;
    int ko = ((sc & 7) ^ (row & 7)) << 3;
    gsrc[t] = (sc >= 8 ? Xl : Xh) + (size_t)(row0 + row) * K + ko;
    ldst[t] = bofs + rb * 128;
  }

  const int nI = K >> 6;   // BK=64 stages; >= 8 at all call sites

#define STAGE(slot, i_)                                              \
  {                                                                  \
    const size_t kb = (size_t)(i_) * 64;                             \
    unsigned short* base_ = LDS + (slot) * 16384;                    \
    GLOAD16(gsrc[0] + kb, base_ + ldst[0]);                          \
    GLOAD16(gsrc[1] + kb, base_ + ldst[1]);                          \
    GLOAD16(gsrc[2] + kb, base_ + ldst[2]);                          \
    GLOAD16(gsrc[3] + kb, base_ + ldst[3]);                          \
  }

  // fragment LDS offsets: wave's K-window = g*32 within the stage
  const int wm = (qw & 1) * 32, wn = (qw >> 1) * 32;
  const int lm = lane & 15, kg4 = lane >> 4;
  const int kg = g * 4 + kg4;
  int aoh[2], boh[2];
#pragma unroll
  for (int mt = 0; mt < 2; ++mt) {
    int ar = wm + mt * 16 + lm;
    aoh[mt] = ar * 128 + ((kg ^ (ar & 7)) << 3);
  }
#pragma unroll
  for (int nt = 0; nt < 2; ++nt) {
    int br = wn + nt * 16 + lm;
    boh[nt] = 8192 + br * 128 + ((kg ^ (br & 7)) << 3);
  }

  STAGE(0, 0);
  STAGE(1, 1);
  STAGE(2, 2);
  for (int i = 0; i < nI; ++i) {
    if (i < nI - 2)      asm volatile("s_waitcnt vmcnt(8)" ::: "memory");
    else if (i < nI - 1) asm volatile("s_waitcnt vmcnt(4)" ::: "memory");
    else                 asm volatile("s_waitcnt vmcnt(0)" ::: "memory");
    __builtin_amdgcn_s_barrier();
    if (i + 3 < nI) STAGE((i + 3) & 3, i + 3);
    const unsigned short* ab = LDS + (i & 3) * 16384;
    s16x8 fah[2], fal[2], fbh[2], fbl[2];
#pragma unroll
    for (int mt = 0; mt < 2; ++mt) {
      fah[mt] = *(const s16x8*)(ab + aoh[mt]);
      fal[mt] = *(const s16x8*)(ab + aoh[mt] + 64);
    }
#pragma unroll
    for (int nt = 0; nt < 2; ++nt) {
      fbh[nt] = *(const s16x8*)(ab + boh[nt]);
      fbl[nt] = *(const s16x8*)(ab + boh[nt] + 64);
    }
    __builtin_amdgcn_s_setprio(1);
#pragma unroll
    for (int mt = 0; mt < 2; ++mt)
#pragma unroll
      for (int nt = 0; nt < 2; ++nt) {
        acc[mt][nt] = __builtin_amdgcn_mfma_f32_16x16x32_bf16(fah[mt], fbh[nt], acc[mt][nt], 0, 0, 0);
        acc[mt][nt] = __builtin_amdgcn_mfma_f32_16x16x32_bf16(fah[mt], fbl[nt], acc[mt][nt], 0, 0, 0);
        acc[mt][nt] = __builtin_amdgcn_mfma_f32_16x16x32_bf16(fal[mt], fbh[nt], acc[mt][nt], 0, 0, 0);
      }
    __builtin_amdgcn_s_setprio(0);
  }
#undef STAGE

  // cross-K-half reduction: g=1 dumps (pad-17), g=0 adds and runs epilogue.
  __builtin_amdgcn_s_barrier();
  float* fred = (float*)LDS;
  const int ridx = (qw * 64 + lane) * 17;
  if (g == 1) {
#pragma unroll
    for (int mt = 0; mt < 2; ++mt)
#pragma unroll
      for (int nt = 0; nt < 2; ++nt)
#pragma unroll
        for (int r = 0; r < 4; ++r)
          fred[ridx + (mt * 2 + nt) * 4 + r] = acc[mt][nt][r];
  }
  __builtin_amdgcn_s_barrier();
  if (g == 0) {
#pragma unroll
    for (int mt = 0; mt < 2; ++mt)
#pragma unroll
      for (int nt = 0; nt < 2; ++nt)
#pragma unroll
        for (int r = 0; r < 4; ++r)
          acc[mt][nt][r] += fred[ridx + (mt * 2 + nt) * 4 + r];
  }
}

// MODE 0: split bf16 out + bias. MODE 1: fp32 out + bias.
template<int MODE>
__global__ __launch_bounds__(512, 1)
void mfma_gemm(const unsigned short* __restrict__ Ah, const unsigned short* __restrict__ Al,
               const unsigned short* __restrict__ BTh, const unsigned short* __restrict__ BTl,
               const float* __restrict__ bias, float* __restrict__ Cf,
               unsigned short* __restrict__ Ch, unsigned short* __restrict__ Cl,
               int M, int N, int K, int gm, int gn)
{
  __shared__ unsigned short LDS[65536];
  int bid = blockIdx.x;
  int xcd = bid & 7, w = bid >> 3;
  int bmi = w % gm, bni = xcd * (gn >> 3) + w / gm;
  long bm = (long)bmi * 64, bn = (long)bni * 64;
  const int tid = threadIdx.x, lane = tid & 63, wave = tid >> 6;
  const int g = wave >> 2, qw = wave & 3;
  f32x4 acc[2][2];
#pragma unroll
  for (int a = 0; a < 2; ++a)
#pragma unroll
    for (int b = 0; b < 2; ++b) acc[a][b] = (f32x4)0.f;
  gemm_core(Ah, Al, BTh, BTl, K, bm, bn, LDS, acc, g, qw);
  if (g == 1) return;

  const int wm = (qw & 1) * 32, wn = (qw >> 1) * 32;
#pragma unroll
  for (int nt = 0; nt < 2; ++nt) {
    int n = (int)bn + wn + nt * 16 + (lane & 15);
    float bv = bias[n];
#pragma unroll
    for (int mt = 0; mt < 2; ++mt) {
      long r0 = bm + wm + mt * 16 + (lane >> 4) * 4;
#pragma unroll
      for (int r = 0; r < 4; ++r) {
        float v = acc[mt][nt][r] + bv;
        long R = r0 + r;
        if (MODE == 0) {
          unsigned short h_, l_; split2(v, h_, l_);
          Ch[R * N + n] = h_; Cl[R * N + n] = l_;
        } else {
          Cf[R * N + n] = v;
        }
      }
    }
  }
}

// combined output GEMM: blockIdx.y selects set; 2 consecutive M-tiles per block
__global__ __launch_bounds__(512, 1)
void out_gemm(const unsigned short* __restrict__ S0h, const unsigned short* __restrict__ S0l,
              const unsigned short* __restrict__ S1h, const unsigned short* __restrict__ S1l,
              const unsigned short* __restrict__ W0h, const unsigned short* __restrict__ W0l,
              const unsigned short* __restrict__ W1h, const unsigned short* __restrict__ W1l,
              const float* __restrict__ bias0, const float* __restrict__ bias1,
              float* __restrict__ out0, float* __restrict__ out1)
{
  __shared__ unsigned short LDS[65536];
  const int set = blockIdx.y;
  const unsigned short* Ah = set ? S1h : S0h;
  const unsigned short* Al = set ? S1l : S0l;
  const unsigned short* BTh = set ? W1h : W0h;
  const unsigned short* BTl = set ? W1l : W0l;
  const float* bias = set ? bias1 : bias0;
  float* Cf = set ? out1 : out0;

  int bid = blockIdx.x;                 // [0,256)
  int xcd = bid & 7, w = bid >> 3;      // w in [0,32)
  long bn = (long)xcd * 64;
  const int tid = threadIdx.x, lane = tid & 63, wave = tid >> 6;
  const int g = wave >> 2, qw = wave & 3;
  const int wm = (qw & 1) * 32, wn = (qw >> 1) * 32;

#pragma unroll
  for (int half = 0; half < 2; ++half) {
    long bm = (long)(w * 2 + half) * 64;
    f32x4 acc[2][2];
#pragma unroll
    for (int a = 0; a < 2; ++a)
#pragma unroll
      for (int b = 0; b < 2; ++b) acc[a][b] = (f32x4)0.f;
    gemm_core(Ah, Al, BTh, BTl, Pn, bm, bn, LDS, acc, g, qw);
    if (g == 0) {
#pragma unroll
      for (int nt = 0; nt < 2; ++nt) {
        int n = (int)bn + wn + nt * 16 + (lane & 15);
        float bv = bias[n];
#pragma unroll
        for (int mt = 0; mt < 2; ++mt) {
          long r0 = bm + wm + mt * 16 + (lane >> 4) * 4;
#pragma unroll
          for (int r = 0; r < 4; ++r) {
            float v = acc[mt][nt][r] + bv;
            long R = r0 + r;
            long t = R >> 9, b = R & 511;
            Cf[(b * TT + t) * DOUT + n] = v;
          }
        }
      }
    }
    __builtin_amdgcn_s_barrier();   // LDS reuse between the two tiles
  }
}

// ---------------- tick kernel (tau >= 1): GEMM + base + NLM epilogue ----------
template<int TAU>
__global__ __launch_bounds__(512, 1)
void tick_mfma(const unsigned short* __restrict__ zh, const unsigned short* __restrict__ zl,
               const unsigned short* __restrict__ WTh, const unsigned short* __restrict__ WTl,
               const float* __restrict__ basep, const float* __restrict__ hist,
               float* __restrict__ histout,
               const float* __restrict__ w1, const float* __restrict__ b1,
               const float* __restrict__ w2, const float* __restrict__ b2,
               unsigned short* __restrict__ zho, unsigned short* __restrict__ zlo,
               unsigned short* __restrict__ zT)
{
  __shared__ unsigned short LDS[65536];
  int bid = blockIdx.x;
  int xcd = bid & 7, w = bid >> 3;
  int bmi = w % 8, bni = xcd * 4 + w / 8;
  long bm = (long)bmi * 64, bn = (long)bni * 64;
  const int tid = threadIdx.x, lane = tid & 63, wave = tid >> 6;
  const int g = wave >> 2, qw = wave & 3;
  f32x4 acc[2][2];
#pragma unroll
  for (int a = 0; a < 2; ++a)
#pragma unroll
    for (int b = 0; b < 2; ++b) acc[a][b] = (f32x4)0.f;
  gemm_core(zh, zl, WTh, WTl, Dn, bm, bn, LDS, acc, g, qw);
  if (g == 1) return;

  const int wm = (qw & 1) * 32, wn = (qw >> 1) * 32;
#pragma unroll
  for (int nt = 0; nt < 2; ++nt) {
    const int d = (int)bn + wn + nt * 16 + (lane & 15);
    float w2v[Hh], b1v[Hh];
#pragma unroll
    for (int hh = 0; hh < Hh; ++hh) {
      w2v[hh] = w2[hh * Dn + d];
      b1v[hh] = b1[hh * Dn + d];
    }
    const float b2v = b2[d];
#pragma unroll
    for (int mt = 0; mt < 2; ++mt) {
      const int b0 = (int)bm + wm + mt * 16 + (lane >> 4) * 4;
      float pre[4], hacc[4][Hh];
#pragma unroll
      for (int r = 0; r < 4; ++r) {
        pre[r] = acc[mt][nt][r] + basep[(size_t)(b0 + r) * Dn + d];
#pragma unroll
        for (int hh = 0; hh < Hh; ++hh) hacc[r][hh] = b1v[hh];
      }
#pragma unroll
      for (int s = 0; s < TAU; ++s) {
        float wv[Hh];
#pragma unroll
        for (int hh = 0; hh < Hh; ++hh) wv[hh] = w1[((15 - TAU + s) * Hh + hh) * Dn + d];
#pragma unroll
        for (int r = 0; r < 4; ++r) {
          float psv = hist[(size_t)s * BD + (size_t)(b0 + r) * Dn + d];
#pragma unroll
          for (int hh = 0; hh < Hh; ++hh) hacc[r][hh] = fmaf(psv, wv[hh], hacc[r][hh]);
        }
      }
      {
        float wv[Hh];
#pragma unroll
        for (int hh = 0; hh < Hh; ++hh) wv[hh] = w1[(15 * Hh + hh) * Dn + d];
#pragma unroll
        for (int r = 0; r < 4; ++r)
#pragma unroll
          for (int hh = 0; hh < Hh; ++hh) hacc[r][hh] = fmaf(pre[r], wv[hh], hacc[r][hh]);
      }
      u16x4 pack;
#pragma unroll
      for (int r = 0; r < 4; ++r) {
        histout[(size_t)(b0 + r) * Dn + d] = pre[r];
        float z = b2v;
#pragma unroll
        for (int hh = 0; hh < Hh; ++hh) z = fmaf(fmaxf(hacc[r][hh], 0.f), w2v[hh], z);
        unsigned short h_, l_; split2(z, h_, l_);
        zho[(size_t)(b0 + r) * Dn + d] = h_;
        zlo[(size_t)(b0 + r) * Dn + d] = l_;
        pack[r] = f2bf(z);
      }
      *(u16x4*)&zT[(size_t)d * Bsz + b0] = pack;
    }
  }
}

// ---------------- tick 0: q-reduce folded; pre = base + q --------------------
__global__ __launch_bounds__(256)
void tick0_kernel(const float* __restrict__ basep, const float* __restrict__ qpart,
                  float* __restrict__ histout,
                  const float* __restrict__ w1, const float* __restrict__ b1,
                  const float* __restrict__ w2, const float* __restrict__ b2,
                  unsigned short* __restrict__ zho, unsigned short* __restrict__ zlo,
                  unsigned short* __restrict__ zT)
{
  int g = blockIdx.x * 256 + threadIdx.x;
  int b = g >> 8;
  int d0 = (g & 255) * 8;
  float qv[8];
#pragma unroll
  for (int k = 0; k < 8; ++k) qv[k] = 0.f;
#pragma unroll
  for (int c = 0; c < 8; ++c) {
    float4 p0 = *(const float4*)(qpart + (size_t)c * Dn + d0);
    float4 p1 = *(const float4*)(qpart + (size_t)c * Dn + d0 + 4);
    qv[0] += p0.x; qv[1] += p0.y; qv[2] += p0.z; qv[3] += p0.w;
    qv[4] += p1.x; qv[5] += p1.y; qv[6] += p1.z; qv[7] += p1.w;
  }
#pragma unroll
  for (int k = 0; k < 8; ++k) {
    int d = d0 + k;
    float pre = basep[(size_t)b * Dn + d] + qv[k];
    histout[(size_t)b * Dn + d] = pre;
    float z = b2[d];
#pragma unroll
    for (int hh = 0; hh < Hh; ++hh) {
      float h = fmaf(pre, w1[(15 * Hh + hh) * Dn + d], b1[hh * Dn + d]);
      z = fmaf(fmaxf(h, 0.f), w2[hh * Dn + d], z);
    }
    unsigned short h_, l_; split2(z, h_, l_);
    zho[(size_t)b * Dn + d] = h_;
    zlo[(size_t)b * Dn + d] = l_;
    zT[(size_t)d * Bsz + b] = f2bf(z);
  }
}

// ---------------- batched sync: S for all ticks, both sets -------------------
__global__ __launch_bounds__(512)
void sync_kernel(const unsigned short* __restrict__ zT,
                 const int* __restrict__ pairs0, const int* __restrict__ pairs1,
                 const float* __restrict__ decay0, const float* __restrict__ decay1,
                 unsigned short* __restrict__ Sh0, unsigned short* __restrict__ Sl0,
                 unsigned short* __restrict__ Sh1, unsigned short* __restrict__ Sl1)
{
  __shared__ float Ls[8][8][65];
  const int set = blockIdx.y;
  const int* pairs = set ? pairs1 : pairs0;
  const float* decay = set ? decay1 : decay0;
  unsigned short* Sh = set ? Sh1 : Sh0;
  unsigned short* Sl = set ? Sl1 : Sl0;
  const int tid = threadIdx.x;
  const int lb = tid & 63, pl = tid >> 6;
  const int p = blockIdx.x * 8 + pl;
  const int i = pairs[2 * p], j = pairs[2 * p + 1];
  const float r = expf(-fabsf(decay[p]));
  const int pb = tid & 7, bb2 = tid >> 3;
  for (int bb = 0; bb < 8; ++bb) {
    int b = bb * 64 + lb;
    float S = 0.f, St[8];
#pragma unroll
    for (int t = 0; t < 8; ++t) {
      float zi = bf2f(zT[(size_t)t * BD + (size_t)i * Bsz + b]);
      float zj = bf2f(zT[(size_t)t * BD + (size_t)j * Bsz + b]);
      S = fmaf(S, r, zi * zj);
      St[t] = S;
    }
#pragma unroll
    for (int t = 0; t < 8; ++t) Ls[pl][t][lb] = St[t];
    __syncthreads();
#pragma unroll
    for (int t = 0; t < 8; ++t) {
      float v = Ls[pb][t][bb2];
      unsigned short h_, l_; split2(v, h_, l_);
      size_t off = ((size_t)t * Bsz + bb * 64 + bb2) * Pn + blockIdx.x * 8 + pb;
      Sh[off] = h_; Sl[off] = l_;
    }
    __syncthreads();
  }
}

// ---------------- fused prep: 5 transpose_splits + x-split + z0 matvec -------
__device__ __forceinline__ void transpose_tile(const float* __restrict__ in, int ldin,
    unsigned short* __restrict__ Th, unsigned short* __restrict__ Tl, int K,
    int kb, int nb, float T[64][65])
{
  int k0 = kb * 64, n0 = nb * 64;
  int tid = threadIdx.x;
  int r = tid >> 2, c0 = (tid & 3) * 16;
#pragma unroll
  for (int cc = 0; cc < 16; cc += 4) {
    float4 v = *(const float4*)(in + (size_t)(k0 + r) * ldin + n0 + c0 + cc);
    T[c0 + cc + 0][r] = v.x; T[c0 + cc + 1][r] = v.y;
    T[c0 + cc + 2][r] = v.z; T[c0 + cc + 3][r] = v.w;
  }
  __syncthreads();
  int n = tid >> 2, kc = (tid & 3) * 16;
#pragma unroll
  for (int kk = 0; kk < 16; ++kk) {
    float v = T[n][kc + kk];
    unsigned short h_, l_; split2(v, h_, l_);
    Th[(size_t)(n0 + n) * K + k0 + kc + kk] = h_;
    Tl[(size_t)(n0 + n) * K + k0 + kc + kk] = l_;
  }
}

__global__ __launch_bounds__(256)
void prep_kernel(const float* __restrict__ W_syn, const float* __restrict__ W_in,
                 const float* __restrict__ W_out, const float* __restrict__ W_act,
                 const float* __restrict__ x, const float* __restrict__ z0,
                 unsigned short* WtTh, unsigned short* WtTl,
                 unsigned short* WbTh, unsigned short* WbTl,
                 unsigned short* WinTh, unsigned short* WinTl,
                 unsigned short* WoTh, unsigned short* WoTl,
                 unsigned short* WaTh, unsigned short* WaTl,
                 unsigned short* xh, unsigned short* xl,
                 float* qpart)
{
  __shared__ float T[64][65];
  const int b = blockIdx.x;
  const int tid = threadIdx.x;
  if (b < 1024) {
    transpose_tile(W_syn, Dn, WtTh, WtTl, Dn, b & 31, b >> 5, T);
  } else if (b < 2048) {
    int b2 = b - 1024;
    transpose_tile(W_syn + (size_t)Dn * Dn, Dn, WbTh, WbTl, Dn, b2 & 31, b2 >> 5, T);
  } else if (b < 2304) {
    int b2 = b - 2048;
    transpose_tile(W_in, Dn, WinTh, WinTl, DIN, b2 & 7, b2 >> 3, T);
  } else if (b < 2368) {
    int b2 = b - 2304;
    transpose_tile(W_out, DOUT, WoTh, WoTl, Pn, b2 & 7, b2 >> 3, T);
  } else if (b < 2432) {
    int b2 = b - 2368;
    transpose_tile(W_act, DOUT, WaTh, WaTl, Pn, b2 & 7, b2 >> 3, T);
  } else if (b < 2688) {
    int i = (b - 2432) * 256 + tid;
    float4 v = *(const float4*)(x + (size_t)i * 4);
    u16x4 h, l;
    unsigned short th, tl;
    split2(v.x, th, tl); h[0] = th; l[0] = tl;
    split2(v.y, th, tl); h[1] = th; l[1] = tl;
    split2(v.z, th, tl); h[2] = th; l[2] = tl;
    split2(v.w, th, tl); h[3] = th; l[3] = tl;
    *(u16x4*)(xh + (size_t)i * 4) = h;
    *(u16x4*)(xl + (size_t)i * 4) = l;
  } else {
    int idx = b - 2688;
    int colb = idx & 31, kc = idx >> 5;
    float (*red)[64] = (float(*)[64])T;
    const int c = tid & 63, strip = tid >> 6;
    const int col = colb * 64 + c;
    const int k0 = (kc * 4 + strip) * 64;
    float acc = 0.f;
#pragma unroll 8
    for (int k = k0; k < k0 + 64; ++k)
      acc = fmaf(z0[k], W_syn[(size_t)k * Dn + col], acc);
    red[strip][c] = acc;
    __syncthreads();
    if (strip == 0)
      qpart[(size_t)kc * Dn + col] = red[0][c] + red[1][c] + red[2][c] + red[3][c];
  }
}

extern "C" void kernel_launch(void* const* d_in, const int* in_sizes, int n_in,
                              void* d_out, int out_size, void* d_ws, size_t ws_size,
                              hipStream_t stream) {
  const float* x      = (const float*)d_in[0];
  const float* W_in   = (const float*)d_in[1];
  const float* b_in   = (const float*)d_in[2];
  const float* z0     = (const float*)d_in[3];
  const float* W_syn  = (const float*)d_in[4];
  const float* b_syn  = (const float*)d_in[5];
  const float* w1     = (const float*)d_in[6];
  const float* b1     = (const float*)d_in[7];
  const float* w2     = (const float*)d_in[8];
  const float* b2     = (const float*)d_in[9];
  const float* decay_out = (const float*)d_in[10];
  const float* decay_act = (const float*)d_in[11];
  const float* W_out  = (const float*)d_in[12];
  const float* b_out  = (const float*)d_in[13];
  const float* W_act  = (const float*)d_in[14];
  const float* b_act  = (const float*)d_in[15];
  const int* pairs_out = (const int*)d_in[16];
  const int* pairs_act = (const int*)d_in[17];

  char* W = (char*)d_ws;
  auto alloc = [&](size_t bytes) { char* p = W; W += (bytes + 255) & ~255ull; return p; };
  unsigned short* WtTh = (unsigned short*)alloc((size_t)Dn * Dn * 2);
  unsigned short* WtTl = (unsigned short*)alloc((size_t)Dn * Dn * 2);
  unsigned short* WbTh = (unsigned short*)alloc((size_t)Dn * Dn * 2);
  unsigned short* WbTl = (unsigned short*)alloc((size_t)Dn * Dn * 2);
  unsigned short* WinTh = (unsigned short*)alloc((size_t)Dn * DIN * 2);
  unsigned short* WinTl = (unsigned short*)alloc((size_t)Dn * DIN * 2);
  unsigned short* WoTh = (unsigned short*)alloc((size_t)DOUT * Pn * 2);
  unsigned short* WoTl = (unsigned short*)alloc((size_t)DOUT * Pn * 2);
  unsigned short* WaTh = (unsigned short*)alloc((size_t)DOUT * Pn * 2);
  unsigned short* WaTl = (unsigned short*)alloc((size_t)DOUT * Pn * 2);
  unsigned short* xh = (unsigned short*)alloc((size_t)Bsz * DIN * 2);
  unsigned short* xl = (unsigned short*)alloc((size_t)Bsz * DIN * 2);
  unsigned short* fh = (unsigned short*)alloc((size_t)BD * 2);
  unsigned short* fl = (unsigned short*)alloc((size_t)BD * 2);
  float* qpart = (float*)alloc(8 * Dn * 4);
  float* base  = (float*)alloc((size_t)BD * 4);
  float* hist  = (float*)alloc((size_t)TT * BD * 4);
  unsigned short* zbh[2], *zbl[2];
  zbh[0] = (unsigned short*)alloc((size_t)BD * 2);
  zbl[0] = (unsigned short*)alloc((size_t)BD * 2);
  zbh[1] = (unsigned short*)alloc((size_t)BD * 2);
  zbl[1] = (unsigned short*)alloc((size_t)BD * 2);
  unsigned short* zT = (unsigned short*)alloc((size_t)TT * BD * 2);
  // S buffers alias the (dead-after-base-GEMM) WbT region: 4MB each
  unsigned short* Sh0 = WbTh;
  unsigned short* Sl0 = WbTh + (size_t)TT * Bsz * Pn;
  unsigned short* Sh1 = WbTl;
  unsigned short* Sl1 = WbTl + (size_t)TT * Bsz * Pn;

  float* outy = (float*)d_out;
  float* outq = outy + (size_t)Bsz * TT * DOUT;

  dim3 blk(256);
  dim3 blk512(512);
  // fused prep
  prep_kernel<<<dim3(2944), blk, 0, stream>>>(
      W_syn, W_in, W_out, W_act, x, z0,
      WtTh, WtTl, WbTh, WbTl, WinTh, WinTl, WoTh, WoTl, WaTh, WaTl,
      xh, xl, qpart);
  // feats = x @ W_in + b_in (split output)
  mfma_gemm<0><<<dim3(256), blk512, 0, stream>>>(xh, xl, WinTh, WinTl, b_in, nullptr, fh, fl,
                                                 Bsz, Dn, DIN, 8, 32);
  // base = feats @ W_syn_bot + b_syn
  mfma_gemm<1><<<dim3(256), blk512, 0, stream>>>(fh, fl, WbTh, WbTl, b_syn, base, nullptr, nullptr,
                                                 Bsz, Dn, Dn, 8, 32);
  // tick 0 (q-reduce folded)
  tick0_kernel<<<dim3(512), blk, 0, stream>>>(base, qpart, hist, w1, b1, w2, b2,
                                              zbh[0], zbl[0], zT);
  // ticks 1..7
  for (int tau = 1; tau < TT; ++tau) {
    const unsigned short* zih = zbh[(tau + 1) & 1];
    const unsigned short* zil = zbl[(tau + 1) & 1];
    unsigned short* zoh = zbh[tau & 1];
    unsigned short* zol = zbl[tau & 1];
    float* ho = hist + (size_t)tau * BD;
    unsigned short* zTo = zT + (size_t)tau * BD;
    switch (tau) {
      case 1: tick_mfma<1><<<dim3(256), blk512, 0, stream>>>(zih, zil, WtTh, WtTl, base, hist, ho, w1, b1, w2, b2, zoh, zol, zTo); break;
      case 2: tick_mfma<2><<<dim3(256), blk512, 0, stream>>>(zih, zil, WtTh, WtTl, base, hist, ho, w1, b1, w2, b2, zoh, zol, zTo); break;
      case 3: tick_mfma<3><<<dim3(256), blk512, 0, stream>>>(zih, zil, WtTh, WtTl, base, hist, ho, w1, b1, w2, b2, zoh, zol, zTo); break;
      case 4: tick_mfma<4><<<dim3(256), blk512, 0, stream>>>(zih, zil, WtTh, WtTl, base, hist, ho, w1, b1, w2, b2, zoh, zol, zTo); break;
      case 5: tick_mfma<5><<<dim3(256), blk512, 0, stream>>>(zih, zil, WtTh, WtTl, base, hist, ho, w1, b1, w2, b2, zoh, zol, zTo); break;
      case 6: tick_mfma<6><<<dim3(256), blk512, 0, stream>>>(zih, zil, WtTh, WtTl, base, hist, ho, w1, b1, w2, b2, zoh, zol, zTo); break;
      case 7: tick_mfma<7><<<dim3(256), blk512, 0, stream>>>(zih, zil, WtTh, WtTl, base, hist, ho, w1, b1, w2, b2, zoh, zol, zTo); break;
    }
  }
  // batched sync for both sets
  sync_kernel<<<dim3(Pn / 8, 2), dim3(512), 0, stream>>>(zT, pairs_out, pairs_act,
                                                         decay_out, decay_act,
                                                         Sh0, Sl0, Sh1, Sl1);
  // both output GEMMs in one launch; 2 M-tiles per block
  out_gemm<<<dim3(256, 2), blk512, 0, stream>>>(Sh0, Sl0, Sh1, Sl1,
                                                WoTh, WoTl, WaTh, WaTl,
                                                b_out, b_act, outy, outq);
}

// Round 17
// 277.468 us; speedup vs baseline: 1.0463x; 1.0463x over previous
//
#include <hip/hip_runtime.h>
#include <math.h>

#define Bsz 512
#define TT 8
#define Dn 2048
#define DIN 512
#define Hh 4
#define Pn 512
#define DOUT 512
#define BD (Bsz*Dn)

typedef __attribute__((ext_vector_type(8))) short s16x8;
typedef __attribute__((ext_vector_type(4))) float f32x4;
typedef __attribute__((ext_vector_type(4))) unsigned short u16x4;

__device__ __forceinline__ unsigned short f2bf(float f) {
  unsigned int u = __float_as_uint(f);
  unsigned int r = (u + 0x7fffu + ((u >> 16) & 1u)) >> 16;
  return (unsigned short)r;
}
__device__ __forceinline__ float bf2f(unsigned short h) {
  return __uint_as_float(((unsigned int)h) << 16);
}
__device__ __forceinline__ void split2(float x, unsigned short& h, unsigned short& l) {
  h = f2bf(x);
  float r = x - bf2f(h);
  l = f2bf(r);
}

// async global->LDS, 16B per lane, LDS dest = wave-uniform base + lane*16
#define GLOAD16(g, l) __builtin_amdgcn_global_load_lds( \
    (const __attribute__((address_space(1))) unsigned int*)(g), \
    (__attribute__((address_space(3))) unsigned int*)(l), 16, 0, 0)

// ---------------- MFMA GEMM core (r15: ring-3 + counted vmcnt — BEST) --------
// 64x64 block tile, 512 threads = 4 quadrant pairs: wave w -> quadrant qw=w&3
// (32x32), K-half g=w>>2 (kg window within each BK=64 stage).
// ONE shared 32KB stage per iter, ring-3 (96KB LDS):
//   iter i: s_waitcnt vmcnt(4) -> s_barrier -> STAGE((i+2)%3, i+2)
//           -> 8 ds_read + 12 MFMA on slot i%3.
// r16's ring-4/vmcnt(8) regressed (L2/queue contention from 3 outstanding
// stages x 256 blocks); ring-3/vmcnt(4) is the measured optimum.
// Reduction: K-half 1 dumps acc (pad-17), K-half 0 adds and owns epilogue.
__device__ __forceinline__ void gemm_core(
    const unsigned short* __restrict__ Ah, const unsigned short* __restrict__ Al,
    const unsigned short* __restrict__ BTh, const unsigned short* __restrict__ BTl,
    int K, long arow0, long brow0,
    unsigned short* LDS, f32x4 acc[2][2], int g, int qw)
{
  const int tid = threadIdx.x;
  const int lane = tid & 63;
  const int lh = lane >> 4, sc = lane & 15;
  // staging: waves 0-3 stage A rows qw*16..+16, waves 4-7 stage B rows qw*16..+16
  const unsigned short* Xh = g ? BTh : Ah;
  const unsigned short* Xl = g ? BTl : Al;
  const long row0 = g ? brow0 : arow0;
  const int bofs = g ? 8192 : 0;
  const unsigned short* gsrc[4];
  int ldst[4];
#pragma unroll
  for (int t = 0; t < 4; ++t) {
    int rb = qw * 16 + t * 4;
    int row = rb + lh;
    int ko = ((sc & 7) ^ (row & 7)) << 3;
    gsrc[t] = (sc >= 8 ? Xl : Xh) + (size_t)(row0 + row) * K + ko;
    ldst[t] = bofs + rb * 128;
  }

  const int nI = K >> 6;   // BK=64 stages; >= 8 at all call sites

#define STAGE(slot, i_)                                              \
  {                                                                  \
    const size_t kb = (size_t)(i_) * 64;                             \
    unsigned short* base_ = LDS + (slot) * 16384;                    \
    GLOAD16(gsrc[0] + kb, base_ + ldst[0]);                          \
    GLOAD16(gsrc[1] + kb, base_ + ldst[1]);                          \
    GLOAD16(gsrc[2] + kb, base_ + ldst[2]);                          \
    GLOAD16(gsrc[3] + kb, base_ + ldst[3]);                          \
  }

  // fragment LDS offsets: wave's K-window = g*32 within the stage
  const int wm = (qw & 1) * 32, wn = (qw >> 1) * 32;
  const int lm = lane & 15, kg4 = lane >> 4;
  const int kg = g * 4 + kg4;
  int aoh[2], boh[2];
#pragma unroll
  for (int mt = 0; mt < 2; ++mt) {
    int ar = wm + mt * 16 + lm;
    aoh[mt] = ar * 128 + ((kg ^ (ar & 7)) << 3);
  }
#pragma unroll
  for (int nt = 0; nt < 2; ++nt) {
    int br = wn + nt * 16 + lm;
    boh[nt] = 8192 + br * 128 + ((kg ^ (br & 7)) << 3);
  }

  STAGE(0, 0);
  STAGE(1, 1);
  int slot = 0, nslot = 2;
  for (int i = 0; i < nI; ++i) {
    if (i < nI - 1) asm volatile("s_waitcnt vmcnt(4)" ::: "memory");
    else            asm volatile("s_waitcnt vmcnt(0)" ::: "memory");
    __builtin_amdgcn_s_barrier();
    if (i + 2 < nI) STAGE(nslot, i + 2);
    const unsigned short* ab = LDS + slot * 16384;
    s16x8 fah[2], fal[2], fbh[2], fbl[2];
#pragma unroll
    for (int mt = 0; mt < 2; ++mt) {
      fah[mt] = *(const s16x8*)(ab + aoh[mt]);
      fal[mt] = *(const s16x8*)(ab + aoh[mt] + 64);
    }
#pragma unroll
    for (int nt = 0; nt < 2; ++nt) {
      fbh[nt] = *(const s16x8*)(ab + boh[nt]);
      fbl[nt] = *(const s16x8*)(ab + boh[nt] + 64);
    }
    __builtin_amdgcn_s_setprio(1);
#pragma unroll
    for (int mt = 0; mt < 2; ++mt)
#pragma unroll
      for (int nt = 0; nt < 2; ++nt) {
        acc[mt][nt] = __builtin_amdgcn_mfma_f32_16x16x32_bf16(fah[mt], fbh[nt], acc[mt][nt], 0, 0, 0);
        acc[mt][nt] = __builtin_amdgcn_mfma_f32_16x16x32_bf16(fah[mt], fbl[nt], acc[mt][nt], 0, 0, 0);
        acc[mt][nt] = __builtin_amdgcn_mfma_f32_16x16x32_bf16(fal[mt], fbh[nt], acc[mt][nt], 0, 0, 0);
      }
    __builtin_amdgcn_s_setprio(0);
    slot = (slot == 2) ? 0 : slot + 1;
    nslot = (nslot == 2) ? 0 : nslot + 1;
  }
#undef STAGE

  // cross-K-half reduction: g=1 dumps (pad-17), g=0 adds and runs epilogue.
  __builtin_amdgcn_s_barrier();
  float* fred = (float*)LDS;
  const int ridx = (qw * 64 + lane) * 17;
  if (g == 1) {
#pragma unroll
    for (int mt = 0; mt < 2; ++mt)
#pragma unroll
      for (int nt = 0; nt < 2; ++nt)
#pragma unroll
        for (int r = 0; r < 4; ++r)
          fred[ridx + (mt * 2 + nt) * 4 + r] = acc[mt][nt][r];
  }
  __builtin_amdgcn_s_barrier();
  if (g == 0) {
#pragma unroll
    for (int mt = 0; mt < 2; ++mt)
#pragma unroll
      for (int nt = 0; nt < 2; ++nt)
#pragma unroll
        for (int r = 0; r < 4; ++r)
          acc[mt][nt][r] += fred[ridx + (mt * 2 + nt) * 4 + r];
  }
}

// MODE 0: split bf16 out + bias. MODE 1: fp32 out + bias.
template<int MODE>
__global__ __launch_bounds__(512, 1)
void mfma_gemm(const unsigned short* __restrict__ Ah, const unsigned short* __restrict__ Al,
               const unsigned short* __restrict__ BTh, const unsigned short* __restrict__ BTl,
               const float* __restrict__ bias, float* __restrict__ Cf,
               unsigned short* __restrict__ Ch, unsigned short* __restrict__ Cl,
               int M, int N, int K, int gm, int gn)
{
  __shared__ unsigned short LDS[49152];
  int bid = blockIdx.x;
  int xcd = bid & 7, w = bid >> 3;
  int bmi = w % gm, bni = xcd * (gn >> 3) + w / gm;
  long bm = (long)bmi * 64, bn = (long)bni * 64;
  const int tid = threadIdx.x, lane = tid & 63, wave = tid >> 6;
  const int g = wave >> 2, qw = wave & 3;
  f32x4 acc[2][2];
#pragma unroll
  for (int a = 0; a < 2; ++a)
#pragma unroll
    for (int b = 0; b < 2; ++b) acc[a][b] = (f32x4)0.f;
  gemm_core(Ah, Al, BTh, BTl, K, bm, bn, LDS, acc, g, qw);
  if (g == 1) return;

  const int wm = (qw & 1) * 32, wn = (qw >> 1) * 32;
#pragma unroll
  for (int nt = 0; nt < 2; ++nt) {
    int n = (int)bn + wn + nt * 16 + (lane & 15);
    float bv = bias[n];
#pragma unroll
    for (int mt = 0; mt < 2; ++mt) {
      long r0 = bm + wm + mt * 16 + (lane >> 4) * 4;
#pragma unroll
      for (int r = 0; r < 4; ++r) {
        float v = acc[mt][nt][r] + bv;
        long R = r0 + r;
        if (MODE == 0) {
          unsigned short h_, l_; split2(v, h_, l_);
          Ch[R * N + n] = h_; Cl[R * N + n] = l_;
        } else {
          Cf[R * N + n] = v;
        }
      }
    }
  }
}

// combined output GEMM: blockIdx.y selects set; 4 consecutive M-tiles per block
// (r17: extends r14's 2-tile amortization; W panel stays hot across all 4).
__global__ __launch_bounds__(512, 1)
void out_gemm(const unsigned short* __restrict__ S0h, const unsigned short* __restrict__ S0l,
              const unsigned short* __restrict__ S1h, const unsigned short* __restrict__ S1l,
              const unsigned short* __restrict__ W0h, const unsigned short* __restrict__ W0l,
              const unsigned short* __restrict__ W1h, const unsigned short* __restrict__ W1l,
              const float* __restrict__ bias0, const float* __restrict__ bias1,
              float* __restrict__ out0, float* __restrict__ out1)
{
  __shared__ unsigned short LDS[49152];
  const int set = blockIdx.y;
  const unsigned short* Ah = set ? S1h : S0h;
  const unsigned short* Al = set ? S1l : S0l;
  const unsigned short* BTh = set ? W1h : W0h;
  const unsigned short* BTl = set ? W1l : W0l;
  const float* bias = set ? bias1 : bias0;
  float* Cf = set ? out1 : out0;

  int bid = blockIdx.x;                 // [0,128)
  int xcd = bid & 7, w = bid >> 3;      // w in [0,16)
  long bn = (long)xcd * 64;
  const int tid = threadIdx.x, lane = tid & 63, wave = tid >> 6;
  const int g = wave >> 2, qw = wave & 3;
  const int wm = (qw & 1) * 32, wn = (qw >> 1) * 32;

#pragma unroll
  for (int q4 = 0; q4 < 4; ++q4) {
    long bm = (long)(w * 4 + q4) * 64;
    f32x4 acc[2][2];
#pragma unroll
    for (int a = 0; a < 2; ++a)
#pragma unroll
      for (int b = 0; b < 2; ++b) acc[a][b] = (f32x4)0.f;
    gemm_core(Ah, Al, BTh, BTl, Pn, bm, bn, LDS, acc, g, qw);
    if (g == 0) {
#pragma unroll
      for (int nt = 0; nt < 2; ++nt) {
        int n = (int)bn + wn + nt * 16 + (lane & 15);
        float bv = bias[n];
#pragma unroll
        for (int mt = 0; mt < 2; ++mt) {
          long r0 = bm + wm + mt * 16 + (lane >> 4) * 4;
#pragma unroll
          for (int r = 0; r < 4; ++r) {
            float v = acc[mt][nt][r] + bv;
            long R = r0 + r;
            long t = R >> 9, b = R & 511;
            Cf[(b * TT + t) * DOUT + n] = v;
          }
        }
      }
    }
    __builtin_amdgcn_s_barrier();   // LDS reuse between tiles
  }
}

// ---------------- tick kernel (tau >= 1): GEMM + base + NLM epilogue ----------
template<int TAU>
__global__ __launch_bounds__(512, 1)
void tick_mfma(const unsigned short* __restrict__ zh, const unsigned short* __restrict__ zl,
               const unsigned short* __restrict__ WTh, const unsigned short* __restrict__ WTl,
               const float* __restrict__ basep, const float* __restrict__ hist,
               float* __restrict__ histout,
               const float* __restrict__ w1, const float* __restrict__ b1,
               const float* __restrict__ w2, const float* __restrict__ b2,
               unsigned short* __restrict__ zho, unsigned short* __restrict__ zlo,
               unsigned short* __restrict__ zT)
{
  __shared__ unsigned short LDS[49152];
  int bid = blockIdx.x;
  int xcd = bid & 7, w = bid >> 3;
  int bmi = w % 8, bni = xcd * 4 + w / 8;
  long bm = (long)bmi * 64, bn = (long)bni * 64;
  const int tid = threadIdx.x, lane = tid & 63, wave = tid >> 6;
  const int g = wave >> 2, qw = wave & 3;
  f32x4 acc[2][2];
#pragma unroll
  for (int a = 0; a < 2; ++a)
#pragma unroll
    for (int b = 0; b < 2; ++b) acc[a][b] = (f32x4)0.f;
  gemm_core(zh, zl, WTh, WTl, Dn, bm, bn, LDS, acc, g, qw);
  if (g == 1) return;

  const int wm = (qw & 1) * 32, wn = (qw >> 1) * 32;
#pragma unroll
  for (int nt = 0; nt < 2; ++nt) {
    const int d = (int)bn + wn + nt * 16 + (lane & 15);
    float w2v[Hh], b1v[Hh];
#pragma unroll
    for (int hh = 0; hh < Hh; ++hh) {
      w2v[hh] = w2[hh * Dn + d];
      b1v[hh] = b1[hh * Dn + d];
    }
    const float b2v = b2[d];
#pragma unroll
    for (int mt = 0; mt < 2; ++mt) {
      const int b0 = (int)bm + wm + mt * 16 + (lane >> 4) * 4;
      float pre[4], hacc[4][Hh];
#pragma unroll
      for (int r = 0; r < 4; ++r) {
        pre[r] = acc[mt][nt][r] + basep[(size_t)(b0 + r) * Dn + d];
#pragma unroll
        for (int hh = 0; hh < Hh; ++hh) hacc[r][hh] = b1v[hh];
      }
#pragma unroll
      for (int s = 0; s < TAU; ++s) {
        float wv[Hh];
#pragma unroll
        for (int hh = 0; hh < Hh; ++hh) wv[hh] = w1[((15 - TAU + s) * Hh + hh) * Dn + d];
#pragma unroll
        for (int r = 0; r < 4; ++r) {
          float psv = hist[(size_t)s * BD + (size_t)(b0 + r) * Dn + d];
#pragma unroll
          for (int hh = 0; hh < Hh; ++hh) hacc[r][hh] = fmaf(psv, wv[hh], hacc[r][hh]);
        }
      }
      {
        float wv[Hh];
#pragma unroll
        for (int hh = 0; hh < Hh; ++hh) wv[hh] = w1[(15 * Hh + hh) * Dn + d];
#pragma unroll
        for (int r = 0; r < 4; ++r)
#pragma unroll
          for (int hh = 0; hh < Hh; ++hh) hacc[r][hh] = fmaf(pre[r], wv[hh], hacc[r][hh]);
      }
      u16x4 pack;
#pragma unroll
      for (int r = 0; r < 4; ++r) {
        histout[(size_t)(b0 + r) * Dn + d] = pre[r];
        float z = b2v;
#pragma unroll
        for (int hh = 0; hh < Hh; ++hh) z = fmaf(fmaxf(hacc[r][hh], 0.f), w2v[hh], z);
        unsigned short h_, l_; split2(z, h_, l_);
        zho[(size_t)(b0 + r) * Dn + d] = h_;
        zlo[(size_t)(b0 + r) * Dn + d] = l_;
        pack[r] = f2bf(z);
      }
      *(u16x4*)&zT[(size_t)d * Bsz + b0] = pack;
    }
  }
}

// ---------------- tick 0: q-reduce folded; pre = base + q --------------------
__global__ __launch_bounds__(256)
void tick0_kernel(const float* __restrict__ basep, const float* __restrict__ qpart,
                  float* __restrict__ histout,
                  const float* __restrict__ w1, const float* __restrict__ b1,
                  const float* __restrict__ w2, const float* __restrict__ b2,
                  unsigned short* __restrict__ zho, unsigned short* __restrict__ zlo,
                  unsigned short* __restrict__ zT)
{
  int g = blockIdx.x * 256 + threadIdx.x;
  int b = g >> 8;
  int d0 = (g & 255) * 8;
  float qv[8];
#pragma unroll
  for (int k = 0; k < 8; ++k) qv[k] = 0.f;
#pragma unroll
  for (int c = 0; c < 8; ++c) {
    float4 p0 = *(const float4*)(qpart + (size_t)c * Dn + d0);
    float4 p1 = *(const float4*)(qpart + (size_t)c * Dn + d0 + 4);
    qv[0] += p0.x; qv[1] += p0.y; qv[2] += p0.z; qv[3] += p0.w;
    qv[4] += p1.x; qv[5] += p1.y; qv[6] += p1.z; qv[7] += p1.w;
  }
#pragma unroll
  for (int k = 0; k < 8; ++k) {
    int d = d0 + k;
    float pre = basep[(size_t)b * Dn + d] + qv[k];
    histout[(size_t)b * Dn + d] = pre;
    float z = b2[d];
#pragma unroll
    for (int hh = 0; hh < Hh; ++hh) {
      float h = fmaf(pre, w1[(15 * Hh + hh) * Dn + d], b1[hh * Dn + d]);
      z = fmaf(fmaxf(h, 0.f), w2[hh * Dn + d], z);
    }
    unsigned short h_, l_; split2(z, h_, l_);
    zho[(size_t)b * Dn + d] = h_;
    zlo[(size_t)b * Dn + d] = l_;
    zT[(size_t)d * Bsz + b] = f2bf(z);
  }
}

// ---------------- batched sync: S for all ticks, both sets -------------------
__global__ __launch_bounds__(512)
void sync_kernel(const unsigned short* __restrict__ zT,
                 const int* __restrict__ pairs0, const int* __restrict__ pairs1,
                 const float* __restrict__ decay0, const float* __restrict__ decay1,
                 unsigned short* __restrict__ Sh0, unsigned short* __restrict__ Sl0,
                 unsigned short* __restrict__ Sh1, unsigned short* __restrict__ Sl1)
{
  __shared__ float Ls[8][8][65];
  const int set = blockIdx.y;
  const int* pairs = set ? pairs1 : pairs0;
  const float* decay = set ? decay1 : decay0;
  unsigned short* Sh = set ? Sh1 : Sh0;
  unsigned short* Sl = set ? Sl1 : Sl0;
  const int tid = threadIdx.x;
  const int lb = tid & 63, pl = tid >> 6;
  const int p = blockIdx.x * 8 + pl;
  const int i = pairs[2 * p], j = pairs[2 * p + 1];
  const float r = expf(-fabsf(decay[p]));
  const int pb = tid & 7, bb2 = tid >> 3;
  for (int bb = 0; bb < 8; ++bb) {
    int b = bb * 64 + lb;
    float S = 0.f, St[8];
#pragma unroll
    for (int t = 0; t < 8; ++t) {
      float zi = bf2f(zT[(size_t)t * BD + (size_t)i * Bsz + b]);
      float zj = bf2f(zT[(size_t)t * BD + (size_t)j * Bsz + b]);
      S = fmaf(S, r, zi * zj);
      St[t] = S;
    }
#pragma unroll
    for (int t = 0; t < 8; ++t) Ls[pl][t][lb] = St[t];
    __syncthreads();
#pragma unroll
    for (int t = 0; t < 8; ++t) {
      float v = Ls[pb][t][bb2];
      unsigned short h_, l_; split2(v, h_, l_);
      size_t off = ((size_t)t * Bsz + bb * 64 + bb2) * Pn + blockIdx.x * 8 + pb;
      Sh[off] = h_; Sl[off] = l_;
    }
    __syncthreads();
  }
}

// ---------------- fused prep: 5 transpose_splits + x-split + z0 matvec -------
__device__ __forceinline__ void transpose_tile(const float* __restrict__ in, int ldin,
    unsigned short* __restrict__ Th, unsigned short* __restrict__ Tl, int K,
    int kb, int nb, float T[64][65])
{
  int k0 = kb * 64, n0 = nb * 64;
  int tid = threadIdx.x;
  int r = tid >> 2, c0 = (tid & 3) * 16;
#pragma unroll
  for (int cc = 0; cc < 16; cc += 4) {
    float4 v = *(const float4*)(in + (size_t)(k0 + r) * ldin + n0 + c0 + cc);
    T[c0 + cc + 0][r] = v.x; T[c0 + cc + 1][r] = v.y;
    T[c0 + cc + 2][r] = v.z; T[c0 + cc + 3][r] = v.w;
  }
  __syncthreads();
  int n = tid >> 2, kc = (tid & 3) * 16;
#pragma unroll
  for (int kk = 0; kk < 16; ++kk) {
    float v = T[n][kc + kk];
    unsigned short h_, l_; split2(v, h_, l_);
    Th[(size_t)(n0 + n) * K + k0 + kc + kk] = h_;
    Tl[(size_t)(n0 + n) * K + k0 + kc + kk] = l_;
  }
}

__global__ __launch_bounds__(256)
void prep_kernel(const float* __restrict__ W_syn, const float* __restrict__ W_in,
                 const float* __restrict__ W_out, const float* __restrict__ W_act,
                 const float* __restrict__ x, const float* __restrict__ z0,
                 unsigned short* WtTh, unsigned short* WtTl,
                 unsigned short* WbTh, unsigned short* WbTl,
                 unsigned short* WinTh, unsigned short* WinTl,
                 unsigned short* WoTh, unsigned short* WoTl,
                 unsigned short* WaTh, unsigned short* WaTl,
                 unsigned short* xh, unsigned short* xl,
                 float* qpart)
{
  __shared__ float T[64][65];
  const int b = blockIdx.x;
  const int tid = threadIdx.x;
  if (b < 1024) {
    transpose_tile(W_syn, Dn, WtTh, WtTl, Dn, b & 31, b >> 5, T);
  } else if (b < 2048) {
    int b2 = b - 1024;
    transpose_tile(W_syn + (size_t)Dn * Dn, Dn, WbTh, WbTl, Dn, b2 & 31, b2 >> 5, T);
  } else if (b < 2304) {
    int b2 = b - 2048;
    transpose_tile(W_in, Dn, WinTh, WinTl, DIN, b2 & 7, b2 >> 3, T);
  } else if (b < 2368) {
    int b2 = b - 2304;
    transpose_tile(W_out, DOUT, WoTh, WoTl, Pn, b2 & 7, b2 >> 3, T);
  } else if (b < 2432) {
    int b2 = b - 2368;
    transpose_tile(W_act, DOUT, WaTh, WaTl, Pn, b2 & 7, b2 >> 3, T);
  } else if (b < 2688) {
    int i = (b - 2432) * 256 + tid;
    float4 v = *(const float4*)(x + (size_t)i * 4);
    u16x4 h, l;
    unsigned short th, tl;
    split2(v.x, th, tl); h[0] = th; l[0] = tl;
    split2(v.y, th, tl); h[1] = th; l[1] = tl;
    split2(v.z, th, tl); h[2] = th; l[2] = tl;
    split2(v.w, th, tl); h[3] = th; l[3] = tl;
    *(u16x4*)(xh + (size_t)i * 4) = h;
    *(u16x4*)(xl + (size_t)i * 4) = l;
  } else {
    int idx = b - 2688;
    int colb = idx & 31, kc = idx >> 5;
    float (*red)[64] = (float(*)[64])T;
    const int c = tid & 63, strip = tid >> 6;
    const int col = colb * 64 + c;
    const int k0 = (kc * 4 + strip) * 64;
    float acc = 0.f;
#pragma unroll 8
    for (int k = k0; k < k0 + 64; ++k)
      acc = fmaf(z0[k], W_syn[(size_t)k * Dn + col], acc);
    red[strip][c] = acc;
    __syncthreads();
    if (strip == 0)
      qpart[(size_t)kc * Dn + col] = red[0][c] + red[1][c] + red[2][c] + red[3][c];
  }
}

extern "C" void kernel_launch(void* const* d_in, const int* in_sizes, int n_in,
                              void* d_out, int out_size, void* d_ws, size_t ws_size,
                              hipStream_t stream) {
  const float* x      = (const float*)d_in[0];
  const float* W_in   = (const float*)d_in[1];
  const float* b_in   = (const float*)d_in[2];
  const float* z0     = (const float*)d_in[3];
  const float* W_syn  = (const float*)d_in[4];
  const float* b_syn  = (const float*)d_in[5];
  const float* w1     = (const float*)d_in[6];
  const float* b1     = (const float*)d_in[7];
  const float* w2     = (const float*)d_in[8];
  const float* b2     = (const float*)d_in[9];
  const float* decay_out = (const float*)d_in[10];
  const float* decay_act = (const float*)d_in[11];
  const float* W_out  = (const float*)d_in[12];
  const float* b_out  = (const float*)d_in[13];
  const float* W_act  = (const float*)d_in[14];
  const float* b_act  = (const float*)d_in[15];
  const int* pairs_out = (const int*)d_in[16];
  const int* pairs_act = (const int*)d_in[17];

  char* W = (char*)d_ws;
  auto alloc = [&](size_t bytes) { char* p = W; W += (bytes + 255) & ~255ull; return p; };
  unsigned short* WtTh = (unsigned short*)alloc((size_t)Dn * Dn * 2);
  unsigned short* WtTl = (unsigned short*)alloc((size_t)Dn * Dn * 2);
  unsigned short* WbTh = (unsigned short*)alloc((size_t)Dn * Dn * 2);
  unsigned short* WbTl = (unsigned short*)alloc((size_t)Dn * Dn * 2);
  unsigned short* WinTh = (unsigned short*)alloc((size_t)Dn * DIN * 2);
  unsigned short* WinTl = (unsigned short*)alloc((size_t)Dn * DIN * 2);
  unsigned short* WoTh = (unsigned short*)alloc((size_t)DOUT * Pn * 2);
  unsigned short* WoTl = (unsigned short*)alloc((size_t)DOUT * Pn * 2);
  unsigned short* WaTh = (unsigned short*)alloc((size_t)DOUT * Pn * 2);
  unsigned short* WaTl = (unsigned short*)alloc((size_t)DOUT * Pn * 2);
  unsigned short* xh = (unsigned short*)alloc((size_t)Bsz * DIN * 2);
  unsigned short* xl = (unsigned short*)alloc((size_t)Bsz * DIN * 2);
  unsigned short* fh = (unsigned short*)alloc((size_t)BD * 2);
  unsigned short* fl = (unsigned short*)alloc((size_t)BD * 2);
  float* qpart = (float*)alloc(8 * Dn * 4);
  float* base  = (float*)alloc((size_t)BD * 4);
  float* hist  = (float*)alloc((size_t)TT * BD * 4);
  unsigned short* zbh[2], *zbl[2];
  zbh[0] = (unsigned short*)alloc((size_t)BD * 2);
  zbl[0] = (unsigned short*)alloc((size_t)BD * 2);
  zbh[1] = (unsigned short*)alloc((size_t)BD * 2);
  zbl[1] = (unsigned short*)alloc((size_t)BD * 2);
  unsigned short* zT = (unsigned short*)alloc((size_t)TT * BD * 2);
  // S buffers alias the (dead-after-base-GEMM) WbT region: 4MB each
  unsigned short* Sh0 = WbTh;
  unsigned short* Sl0 = WbTh + (size_t)TT * Bsz * Pn;
  unsigned short* Sh1 = WbTl;
  unsigned short* Sl1 = WbTl + (size_t)TT * Bsz * Pn;

  float* outy = (float*)d_out;
  float* outq = outy + (size_t)Bsz * TT * DOUT;

  dim3 blk(256);
  dim3 blk512(512);
  // fused prep
  prep_kernel<<<dim3(2944), blk, 0, stream>>>(
      W_syn, W_in, W_out, W_act, x, z0,
      WtTh, WtTl, WbTh, WbTl, WinTh, WinTl, WoTh, WoTl, WaTh, WaTl,
      xh, xl, qpart);
  // feats = x @ W_in + b_in (split output)
  mfma_gemm<0><<<dim3(256), blk512, 0, stream>>>(xh, xl, WinTh, WinTl, b_in, nullptr, fh, fl,
                                                 Bsz, Dn, DIN, 8, 32);
  // base = feats @ W_syn_bot + b_syn
  mfma_gemm<1><<<dim3(256), blk512, 0, stream>>>(fh, fl, WbTh, WbTl, b_syn, base, nullptr, nullptr,
                                                 Bsz, Dn, Dn, 8, 32);
  // tick 0 (q-reduce folded)
  tick0_kernel<<<dim3(512), blk, 0, stream>>>(base, qpart, hist, w1, b1, w2, b2,
                                              zbh[0], zbl[0], zT);
  // ticks 1..7
  for (int tau = 1; tau < TT; ++tau) {
    const unsigned short* zih = zbh[(tau + 1) & 1];
    const unsigned short* zil = zbl[(tau + 1) & 1];
    unsigned short* zoh = zbh[tau & 1];
    unsigned short* zol = zbl[tau & 1];
    float* ho = hist + (size_t)tau * BD;
    unsigned short* zTo = zT + (size_t)tau * BD;
    switch (tau) {
      case 1: tick_mfma<1><<<dim3(256), blk512, 0, stream>>>(zih, zil, WtTh, WtTl, base, hist, ho, w1, b1, w2, b2, zoh, zol, zTo); break;
      case 2: tick_mfma<2><<<dim3(256), blk512, 0, stream>>>(zih, zil, WtTh, WtTl, base, hist, ho, w1, b1, w2, b2, zoh, zol, zTo); break;
      case 3: tick_mfma<3><<<dim3(256), blk512, 0, stream>>>(zih, zil, WtTh, WtTl, base, hist, ho, w1, b1, w2, b2, zoh, zol, zTo); break;
      case 4: tick_mfma<4><<<dim3(256), blk512, 0, stream>>>(zih, zil, WtTh, WtTl, base, hist, ho, w1, b1, w2, b2, zoh, zol, zTo); break;
      case 5: tick_mfma<5><<<dim3(256), blk512, 0, stream>>>(zih, zil, WtTh, WtTl, base, hist, ho, w1, b1, w2, b2, zoh, zol, zTo); break;
      case 6: tick_mfma<6><<<dim3(256), blk512, 0, stream>>>(zih, zil, WtTh, WtTl, base, hist, ho, w1, b1, w2, b2, zoh, zol, zTo); break;
      case 7: tick_mfma<7><<<dim3(256), blk512, 0, stream>>>(zih, zil, WtTh, WtTl, base, hist, ho, w1, b1, w2, b2, zoh, zol, zTo); break;
    }
  }
  // batched sync for both sets
  sync_kernel<<<dim3(Pn / 8, 2), dim3(512), 0, stream>>>(zT, pairs_out, pairs_act,
                                                         decay_out, decay_act,
                                                         Sh0, Sl0, Sh1, Sl1);
  // both output GEMMs in one launch; 4 M-tiles per block
  out_gemm<<<dim3(128, 2), blk512, 0, stream>>>(Sh0, Sl0, Sh1, Sl1,
                                                WoTh, WoTl, WaTh, WaTl,
                                                b_out, b_act, outy, outq);
}

// Round 18
// 276.377 us; speedup vs baseline: 1.0504x; 1.0039x over previous
//
#include <hip/hip_runtime.h>
#include <math.h>

#define Bsz 512
#define TT 8
#define Dn 2048
#define DIN 512
#define Hh 4
#define Pn 512
#define DOUT 512
#define BD (Bsz*Dn)

typedef __attribute__((ext_vector_type(8))) short s16x8;
typedef __attribute__((ext_vector_type(4))) float f32x4;
typedef __attribute__((ext_vector_type(4))) unsigned short u16x4;
typedef __attribute__((ext_vector_type(8))) unsigned short u16x8;

__device__ __forceinline__ unsigned short f2bf(float f) {
  unsigned int u = __float_as_uint(f);
  unsigned int r = (u + 0x7fffu + ((u >> 16) & 1u)) >> 16;
  return (unsigned short)r;
}
__device__ __forceinline__ float bf2f(unsigned short h) {
  return __uint_as_float(((unsigned int)h) << 16);
}
__device__ __forceinline__ void split2(float x, unsigned short& h, unsigned short& l) {
  h = f2bf(x);
  float r = x - bf2f(h);
  l = f2bf(r);
}

// async global->LDS, 16B per lane, LDS dest = wave-uniform base + lane*16
#define GLOAD16(g, l) __builtin_amdgcn_global_load_lds( \
    (const __attribute__((address_space(1))) unsigned int*)(g), \
    (__attribute__((address_space(3))) unsigned int*)(l), 16, 0, 0)

// ---------------- MFMA GEMM core (r15: ring-3 + counted vmcnt — BEST) --------
// 64x64 block tile, 512 threads = 4 quadrant pairs: wave w -> quadrant qw=w&3
// (32x32), K-half g=w>>2 (kg window within each BK=64 stage).
// ONE shared 32KB stage per iter, ring-3 (96KB LDS):
//   iter i: s_waitcnt vmcnt(4) -> s_barrier -> STAGE((i+2)%3, i+2)
//           -> 8 ds_read + 12 MFMA on slot i%3.
// r16's ring-4/vmcnt(8) regressed (L2/queue contention); ring-3/vmcnt(4) is
// the measured optimum of the schedule-depth axis (r10 shallower also worse).
// Reduction: K-half 1 dumps acc (pad-17), K-half 0 adds and owns epilogue.
__device__ __forceinline__ void gemm_core(
    const unsigned short* __restrict__ Ah, const unsigned short* __restrict__ Al,
    const unsigned short* __restrict__ BTh, const unsigned short* __restrict__ BTl,
    int K, long arow0, long brow0,
    unsigned short* LDS, f32x4 acc[2][2], int g, int qw)
{
  const int tid = threadIdx.x;
  const int lane = tid & 63;
  const int lh = lane >> 4, sc = lane & 15;
  // staging: waves 0-3 stage A rows qw*16..+16, waves 4-7 stage B rows qw*16..+16
  const unsigned short* Xh = g ? BTh : Ah;
  const unsigned short* Xl = g ? BTl : Al;
  const long row0 = g ? brow0 : arow0;
  const int bofs = g ? 8192 : 0;
  const unsigned short* gsrc[4];
  int ldst[4];
#pragma unroll
  for (int t = 0; t < 4; ++t) {
    int rb = qw * 16 + t * 4;
    int row = rb + lh;
    int ko = ((sc & 7) ^ (row & 7)) << 3;
    gsrc[t] = (sc >= 8 ? Xl : Xh) + (size_t)(row0 + row) * K + ko;
    ldst[t] = bofs + rb * 128;
  }

  const int nI = K >> 6;   // BK=64 stages; >= 8 at all call sites

#define STAGE(slot, i_)                                              \
  {                                                                  \
    const size_t kb = (size_t)(i_) * 64;                             \
    unsigned short* base_ = LDS + (slot) * 16384;                    \
    GLOAD16(gsrc[0] + kb, base_ + ldst[0]);                          \
    GLOAD16(gsrc[1] + kb, base_ + ldst[1]);                          \
    GLOAD16(gsrc[2] + kb, base_ + ldst[2]);                          \
    GLOAD16(gsrc[3] + kb, base_ + ldst[3]);                          \
  }

  // fragment LDS offsets: wave's K-window = g*32 within the stage
  const int wm = (qw & 1) * 32, wn = (qw >> 1) * 32;
  const int lm = lane & 15, kg4 = lane >> 4;
  const int kg = g * 4 + kg4;
  int aoh[2], boh[2];
#pragma unroll
  for (int mt = 0; mt < 2; ++mt) {
    int ar = wm + mt * 16 + lm;
    aoh[mt] = ar * 128 + ((kg ^ (ar & 7)) << 3);
  }
#pragma unroll
  for (int nt = 0; nt < 2; ++nt) {
    int br = wn + nt * 16 + lm;
    boh[nt] = 8192 + br * 128 + ((kg ^ (br & 7)) << 3);
  }

  STAGE(0, 0);
  STAGE(1, 1);
  int slot = 0, nslot = 2;
  for (int i = 0; i < nI; ++i) {
    if (i < nI - 1) asm volatile("s_waitcnt vmcnt(4)" ::: "memory");
    else            asm volatile("s_waitcnt vmcnt(0)" ::: "memory");
    __builtin_amdgcn_s_barrier();
    if (i + 2 < nI) STAGE(nslot, i + 2);
    const unsigned short* ab = LDS + slot * 16384;
    s16x8 fah[2], fal[2], fbh[2], fbl[2];
#pragma unroll
    for (int mt = 0; mt < 2; ++mt) {
      fah[mt] = *(const s16x8*)(ab + aoh[mt]);
      fal[mt] = *(const s16x8*)(ab + aoh[mt] + 64);
    }
#pragma unroll
    for (int nt = 0; nt < 2; ++nt) {
      fbh[nt] = *(const s16x8*)(ab + boh[nt]);
      fbl[nt] = *(const s16x8*)(ab + boh[nt] + 64);
    }
    __builtin_amdgcn_s_setprio(1);
#pragma unroll
    for (int mt = 0; mt < 2; ++mt)
#pragma unroll
      for (int nt = 0; nt < 2; ++nt) {
        acc[mt][nt] = __builtin_amdgcn_mfma_f32_16x16x32_bf16(fah[mt], fbh[nt], acc[mt][nt], 0, 0, 0);
        acc[mt][nt] = __builtin_amdgcn_mfma_f32_16x16x32_bf16(fah[mt], fbl[nt], acc[mt][nt], 0, 0, 0);
        acc[mt][nt] = __builtin_amdgcn_mfma_f32_16x16x32_bf16(fal[mt], fbh[nt], acc[mt][nt], 0, 0, 0);
      }
    __builtin_amdgcn_s_setprio(0);
    slot = (slot == 2) ? 0 : slot + 1;
    nslot = (nslot == 2) ? 0 : nslot + 1;
  }
#undef STAGE

  // cross-K-half reduction: g=1 dumps (pad-17), g=0 adds and runs epilogue.
  __builtin_amdgcn_s_barrier();
  float* fred = (float*)LDS;
  const int ridx = (qw * 64 + lane) * 17;
  if (g == 1) {
#pragma unroll
    for (int mt = 0; mt < 2; ++mt)
#pragma unroll
      for (int nt = 0; nt < 2; ++nt)
#pragma unroll
        for (int r = 0; r < 4; ++r)
          fred[ridx + (mt * 2 + nt) * 4 + r] = acc[mt][nt][r];
  }
  __builtin_amdgcn_s_barrier();
  if (g == 0) {
#pragma unroll
    for (int mt = 0; mt < 2; ++mt)
#pragma unroll
      for (int nt = 0; nt < 2; ++nt)
#pragma unroll
        for (int r = 0; r < 4; ++r)
          acc[mt][nt][r] += fred[ridx + (mt * 2 + nt) * 4 + r];
  }
}

// MODE 0: split bf16 out + bias. MODE 1: fp32 out + bias.
template<int MODE>
__global__ __launch_bounds__(512, 1)
void mfma_gemm(const unsigned short* __restrict__ Ah, const unsigned short* __restrict__ Al,
               const unsigned short* __restrict__ BTh, const unsigned short* __restrict__ BTl,
               const float* __restrict__ bias, float* __restrict__ Cf,
               unsigned short* __restrict__ Ch, unsigned short* __restrict__ Cl,
               int M, int N, int K, int gm, int gn)
{
  __shared__ unsigned short LDS[49152];
  int bid = blockIdx.x;
  int xcd = bid & 7, w = bid >> 3;
  int bmi = w % gm, bni = xcd * (gn >> 3) + w / gm;
  long bm = (long)bmi * 64, bn = (long)bni * 64;
  const int tid = threadIdx.x, lane = tid & 63, wave = tid >> 6;
  const int g = wave >> 2, qw = wave & 3;
  f32x4 acc[2][2];
#pragma unroll
  for (int a = 0; a < 2; ++a)
#pragma unroll
    for (int b = 0; b < 2; ++b) acc[a][b] = (f32x4)0.f;
  gemm_core(Ah, Al, BTh, BTl, K, bm, bn, LDS, acc, g, qw);
  if (g == 1) return;

  const int wm = (qw & 1) * 32, wn = (qw >> 1) * 32;
#pragma unroll
  for (int nt = 0; nt < 2; ++nt) {
    int n = (int)bn + wn + nt * 16 + (lane & 15);
    float bv = bias[n];
#pragma unroll
    for (int mt = 0; mt < 2; ++mt) {
      long r0 = bm + wm + mt * 16 + (lane >> 4) * 4;
#pragma unroll
      for (int r = 0; r < 4; ++r) {
        float v = acc[mt][nt][r] + bv;
        long R = r0 + r;
        if (MODE == 0) {
          unsigned short h_, l_; split2(v, h_, l_);
          Ch[R * N + n] = h_; Cl[R * N + n] = l_;
        } else {
          Cf[R * N + n] = v;
        }
      }
    }
  }
}

// combined output GEMM: blockIdx.y selects set; 4 consecutive M-tiles per block
__global__ __launch_bounds__(512, 1)
void out_gemm(const unsigned short* __restrict__ S0h, const unsigned short* __restrict__ S0l,
              const unsigned short* __restrict__ S1h, const unsigned short* __restrict__ S1l,
              const unsigned short* __restrict__ W0h, const unsigned short* __restrict__ W0l,
              const unsigned short* __restrict__ W1h, const unsigned short* __restrict__ W1l,
              const float* __restrict__ bias0, const float* __restrict__ bias1,
              float* __restrict__ out0, float* __restrict__ out1)
{
  __shared__ unsigned short LDS[49152];
  const int set = blockIdx.y;
  const unsigned short* Ah = set ? S1h : S0h;
  const unsigned short* Al = set ? S1l : S0l;
  const unsigned short* BTh = set ? W1h : W0h;
  const unsigned short* BTl = set ? W1l : W0l;
  const float* bias = set ? bias1 : bias0;
  float* Cf = set ? out1 : out0;

  int bid = blockIdx.x;                 // [0,128)
  int xcd = bid & 7, w = bid >> 3;      // w in [0,16)
  long bn = (long)xcd * 64;
  const int tid = threadIdx.x, lane = tid & 63, wave = tid >> 6;
  const int g = wave >> 2, qw = wave & 3;
  const int wm = (qw & 1) * 32, wn = (qw >> 1) * 32;

#pragma unroll
  for (int q4 = 0; q4 < 4; ++q4) {
    long bm = (long)(w * 4 + q4) * 64;
    f32x4 acc[2][2];
#pragma unroll
    for (int a = 0; a < 2; ++a)
#pragma unroll
      for (int b = 0; b < 2; ++b) acc[a][b] = (f32x4)0.f;
    gemm_core(Ah, Al, BTh, BTl, Pn, bm, bn, LDS, acc, g, qw);
    if (g == 0) {
#pragma unroll
      for (int nt = 0; nt < 2; ++nt) {
        int n = (int)bn + wn + nt * 16 + (lane & 15);
        float bv = bias[n];
#pragma unroll
        for (int mt = 0; mt < 2; ++mt) {
          long r0 = bm + wm + mt * 16 + (lane >> 4) * 4;
#pragma unroll
          for (int r = 0; r < 4; ++r) {
            float v = acc[mt][nt][r] + bv;
            long R = r0 + r;
            long t = R >> 9, b = R & 511;
            Cf[(b * TT + t) * DOUT + n] = v;
          }
        }
      }
    }
    __builtin_amdgcn_s_barrier();   // LDS reuse between tiles
  }
}

// ---------------- tick kernel (tau >= 1): GEMM + base + NLM epilogue ----------
template<int TAU>
__global__ __launch_bounds__(512, 1)
void tick_mfma(const unsigned short* __restrict__ zh, const unsigned short* __restrict__ zl,
               const unsigned short* __restrict__ WTh, const unsigned short* __restrict__ WTl,
               const float* __restrict__ basep, const float* __restrict__ hist,
               float* __restrict__ histout,
               const float* __restrict__ w1, const float* __restrict__ b1,
               const float* __restrict__ w2, const float* __restrict__ b2,
               unsigned short* __restrict__ zho, unsigned short* __restrict__ zlo,
               unsigned short* __restrict__ zT)
{
  __shared__ unsigned short LDS[49152];
  int bid = blockIdx.x;
  int xcd = bid & 7, w = bid >> 3;
  int bmi = w % 8, bni = xcd * 4 + w / 8;
  long bm = (long)bmi * 64, bn = (long)bni * 64;
  const int tid = threadIdx.x, lane = tid & 63, wave = tid >> 6;
  const int g = wave >> 2, qw = wave & 3;
  f32x4 acc[2][2];
#pragma unroll
  for (int a = 0; a < 2; ++a)
#pragma unroll
    for (int b = 0; b < 2; ++b) acc[a][b] = (f32x4)0.f;
  gemm_core(zh, zl, WTh, WTl, Dn, bm, bn, LDS, acc, g, qw);
  if (g == 1) return;

  const int wm = (qw & 1) * 32, wn = (qw >> 1) * 32;
#pragma unroll
  for (int nt = 0; nt < 2; ++nt) {
    const int d = (int)bn + wn + nt * 16 + (lane & 15);
    float w2v[Hh], b1v[Hh];
#pragma unroll
    for (int hh = 0; hh < Hh; ++hh) {
      w2v[hh] = w2[hh * Dn + d];
      b1v[hh] = b1[hh * Dn + d];
    }
    const float b2v = b2[d];
#pragma unroll
    for (int mt = 0; mt < 2; ++mt) {
      const int b0 = (int)bm + wm + mt * 16 + (lane >> 4) * 4;
      float pre[4], hacc[4][Hh];
#pragma unroll
      for (int r = 0; r < 4; ++r) {
        pre[r] = acc[mt][nt][r] + basep[(size_t)(b0 + r) * Dn + d];
#pragma unroll
        for (int hh = 0; hh < Hh; ++hh) hacc[r][hh] = b1v[hh];
      }
#pragma unroll
      for (int s = 0; s < TAU; ++s) {
        float wv[Hh];
#pragma unroll
        for (int hh = 0; hh < Hh; ++hh) wv[hh] = w1[((15 - TAU + s) * Hh + hh) * Dn + d];
#pragma unroll
        for (int r = 0; r < 4; ++r) {
          float psv = hist[(size_t)s * BD + (size_t)(b0 + r) * Dn + d];
#pragma unroll
          for (int hh = 0; hh < Hh; ++hh) hacc[r][hh] = fmaf(psv, wv[hh], hacc[r][hh]);
        }
      }
      {
        float wv[Hh];
#pragma unroll
        for (int hh = 0; hh < Hh; ++hh) wv[hh] = w1[(15 * Hh + hh) * Dn + d];
#pragma unroll
        for (int r = 0; r < 4; ++r)
#pragma unroll
          for (int hh = 0; hh < Hh; ++hh) hacc[r][hh] = fmaf(pre[r], wv[hh], hacc[r][hh]);
      }
      u16x4 pack;
#pragma unroll
      for (int r = 0; r < 4; ++r) {
        histout[(size_t)(b0 + r) * Dn + d] = pre[r];
        float z = b2v;
#pragma unroll
        for (int hh = 0; hh < Hh; ++hh) z = fmaf(fmaxf(hacc[r][hh], 0.f), w2v[hh], z);
        unsigned short h_, l_; split2(z, h_, l_);
        zho[(size_t)(b0 + r) * Dn + d] = h_;
        zlo[(size_t)(b0 + r) * Dn + d] = l_;
        pack[r] = f2bf(z);
      }
      *(u16x4*)&zT[(size_t)d * Bsz + b0] = pack;
    }
  }
}

// ---------------- tick 0: q-reduce folded; pre = base + q --------------------
__global__ __launch_bounds__(256)
void tick0_kernel(const float* __restrict__ basep, const float* __restrict__ qpart,
                  float* __restrict__ histout,
                  const float* __restrict__ w1, const float* __restrict__ b1,
                  const float* __restrict__ w2, const float* __restrict__ b2,
                  unsigned short* __restrict__ zho, unsigned short* __restrict__ zlo,
                  unsigned short* __restrict__ zT)
{
  int g = blockIdx.x * 256 + threadIdx.x;
  int b = g >> 8;
  int d0 = (g & 255) * 8;
  float qv[8];
#pragma unroll
  for (int k = 0; k < 8; ++k) qv[k] = 0.f;
#pragma unroll
  for (int c = 0; c < 8; ++c) {
    float4 p0 = *(const float4*)(qpart + (size_t)c * Dn + d0);
    float4 p1 = *(const float4*)(qpart + (size_t)c * Dn + d0 + 4);
    qv[0] += p0.x; qv[1] += p0.y; qv[2] += p0.z; qv[3] += p0.w;
    qv[4] += p1.x; qv[5] += p1.y; qv[6] += p1.z; qv[7] += p1.w;
  }
#pragma unroll
  for (int k = 0; k < 8; ++k) {
    int d = d0 + k;
    float pre = basep[(size_t)b * Dn + d] + qv[k];
    histout[(size_t)b * Dn + d] = pre;
    float z = b2[d];
#pragma unroll
    for (int hh = 0; hh < Hh; ++hh) {
      float h = fmaf(pre, w1[(15 * Hh + hh) * Dn + d], b1[hh * Dn + d]);
      z = fmaf(fmaxf(h, 0.f), w2[hh * Dn + d], z);
    }
    unsigned short h_, l_; split2(z, h_, l_);
    zho[(size_t)b * Dn + d] = h_;
    zlo[(size_t)b * Dn + d] = l_;
    zT[(size_t)d * Bsz + b] = f2bf(z);
  }
}

// ---------------- batched sync: S for all ticks, both sets -------------------
// r18: bb loop split across blockIdx.z (64x2x2 = 256 blocks; was 128 blocks
// covering half the CUs on a latency-bound scattered gather).
__global__ __launch_bounds__(512)
void sync_kernel(const unsigned short* __restrict__ zT,
                 const int* __restrict__ pairs0, const int* __restrict__ pairs1,
                 const float* __restrict__ decay0, const float* __restrict__ decay1,
                 unsigned short* __restrict__ Sh0, unsigned short* __restrict__ Sl0,
                 unsigned short* __restrict__ Sh1, unsigned short* __restrict__ Sl1)
{
  __shared__ float Ls[8][8][65];
  const int set = blockIdx.y;
  const int* pairs = set ? pairs1 : pairs0;
  const float* decay = set ? decay1 : decay0;
  unsigned short* Sh = set ? Sh1 : Sh0;
  unsigned short* Sl = set ? Sl1 : Sl0;
  const int tid = threadIdx.x;
  const int lb = tid & 63, pl = tid >> 6;
  const int p = blockIdx.x * 8 + pl;
  const int i = pairs[2 * p], j = pairs[2 * p + 1];
  const float r = expf(-fabsf(decay[p]));
  const int pb = tid & 7, bb2 = tid >> 3;
  const int bb0 = blockIdx.z * 4;
  for (int bb = bb0; bb < bb0 + 4; ++bb) {
    int b = bb * 64 + lb;
    float S = 0.f, St[8];
#pragma unroll
    for (int t = 0; t < 8; ++t) {
      float zi = bf2f(zT[(size_t)t * BD + (size_t)i * Bsz + b]);
      float zj = bf2f(zT[(size_t)t * BD + (size_t)j * Bsz + b]);
      S = fmaf(S, r, zi * zj);
      St[t] = S;
    }
#pragma unroll
    for (int t = 0; t < 8; ++t) Ls[pl][t][lb] = St[t];
    __syncthreads();
#pragma unroll
    for (int t = 0; t < 8; ++t) {
      float v = Ls[pb][t][bb2];
      unsigned short h_, l_; split2(v, h_, l_);
      size_t off = ((size_t)t * Bsz + bb * 64 + bb2) * Pn + blockIdx.x * 8 + pb;
      Sh[off] = h_; Sl[off] = l_;
    }
    __syncthreads();
  }
}

// ---------------- fused prep: 5 transpose_splits + x-split + z0 matvec -------
// r18: bf16 outputs stored as u16x8 vectors (2x 16B stores per matrix per
// thread, was 16 scalar 2B stores — G13).
__device__ __forceinline__ void transpose_tile(const float* __restrict__ in, int ldin,
    unsigned short* __restrict__ Th, unsigned short* __restrict__ Tl, int K,
    int kb, int nb, float T[64][65])
{
  int k0 = kb * 64, n0 = nb * 64;
  int tid = threadIdx.x;
  int r = tid >> 2, c0 = (tid & 3) * 16;
#pragma unroll
  for (int cc = 0; cc < 16; cc += 4) {
    float4 v = *(const float4*)(in + (size_t)(k0 + r) * ldin + n0 + c0 + cc);
    T[c0 + cc + 0][r] = v.x; T[c0 + cc + 1][r] = v.y;
    T[c0 + cc + 2][r] = v.z; T[c0 + cc + 3][r] = v.w;
  }
  __syncthreads();
  int n = tid >> 2, kc = (tid & 3) * 16;
#pragma unroll
  for (int half = 0; half < 2; ++half) {
    u16x8 vh, vl;
#pragma unroll
    for (int kk = 0; kk < 8; ++kk) {
      float v = T[n][kc + half * 8 + kk];
      unsigned short h_, l_; split2(v, h_, l_);
      vh[kk] = h_; vl[kk] = l_;
    }
    *(u16x8*)&Th[(size_t)(n0 + n) * K + k0 + kc + half * 8] = vh;
    *(u16x8*)&Tl[(size_t)(n0 + n) * K + k0 + kc + half * 8] = vl;
  }
}

__global__ __launch_bounds__(256)
void prep_kernel(const float* __restrict__ W_syn, const float* __restrict__ W_in,
                 const float* __restrict__ W_out, const float* __restrict__ W_act,
                 const float* __restrict__ x, const float* __restrict__ z0,
                 unsigned short* WtTh, unsigned short* WtTl,
                 unsigned short* WbTh, unsigned short* WbTl,
                 unsigned short* WinTh, unsigned short* WinTl,
                 unsigned short* WoTh, unsigned short* WoTl,
                 unsigned short* WaTh, unsigned short* WaTl,
                 unsigned short* xh, unsigned short* xl,
                 float* qpart)
{
  __shared__ float T[64][65];
  const int b = blockIdx.x;
  const int tid = threadIdx.x;
  if (b < 1024) {
    transpose_tile(W_syn, Dn, WtTh, WtTl, Dn, b & 31, b >> 5, T);
  } else if (b < 2048) {
    int b2 = b - 1024;
    transpose_tile(W_syn + (size_t)Dn * Dn, Dn, WbTh, WbTl, Dn, b2 & 31, b2 >> 5, T);
  } else if (b < 2304) {
    int b2 = b - 2048;
    transpose_tile(W_in, Dn, WinTh, WinTl, DIN, b2 & 7, b2 >> 3, T);
  } else if (b < 2368) {
    int b2 = b - 2304;
    transpose_tile(W_out, DOUT, WoTh, WoTl, Pn, b2 & 7, b2 >> 3, T);
  } else if (b < 2432) {
    int b2 = b - 2368;
    transpose_tile(W_act, DOUT, WaTh, WaTl, Pn, b2 & 7, b2 >> 3, T);
  } else if (b < 2688) {
    int i = (b - 2432) * 256 + tid;
    float4 v = *(const float4*)(x + (size_t)i * 4);
    u16x4 h, l;
    unsigned short th, tl;
    split2(v.x, th, tl); h[0] = th; l[0] = tl;
    split2(v.y, th, tl); h[1] = th; l[1] = tl;
    split2(v.z, th, tl); h[2] = th; l[2] = tl;
    split2(v.w, th, tl); h[3] = th; l[3] = tl;
    *(u16x4*)(xh + (size_t)i * 4) = h;
    *(u16x4*)(xl + (size_t)i * 4) = l;
  } else {
    int idx = b - 2688;
    int colb = idx & 31, kc = idx >> 5;
    float (*red)[64] = (float(*)[64])T;
    const int c = tid & 63, strip = tid >> 6;
    const int col = colb * 64 + c;
    const int k0 = (kc * 4 + strip) * 64;
    float acc = 0.f;
#pragma unroll 8
    for (int k = k0; k < k0 + 64; ++k)
      acc = fmaf(z0[k], W_syn[(size_t)k * Dn + col], acc);
    red[strip][c] = acc;
    __syncthreads();
    if (strip == 0)
      qpart[(size_t)kc * Dn + col] = red[0][c] + red[1][c] + red[2][c] + red[3][c];
  }
}

extern "C" void kernel_launch(void* const* d_in, const int* in_sizes, int n_in,
                              void* d_out, int out_size, void* d_ws, size_t ws_size,
                              hipStream_t stream) {
  const float* x      = (const float*)d_in[0];
  const float* W_in   = (const float*)d_in[1];
  const float* b_in   = (const float*)d_in[2];
  const float* z0     = (const float*)d_in[3];
  const float* W_syn  = (const float*)d_in[4];
  const float* b_syn  = (const float*)d_in[5];
  const float* w1     = (const float*)d_in[6];
  const float* b1     = (const float*)d_in[7];
  const float* w2     = (const float*)d_in[8];
  const float* b2     = (const float*)d_in[9];
  const float* decay_out = (const float*)d_in[10];
  const float* decay_act = (const float*)d_in[11];
  const float* W_out  = (const float*)d_in[12];
  const float* b_out  = (const float*)d_in[13];
  const float* W_act  = (const float*)d_in[14];
  const float* b_act  = (const float*)d_in[15];
  const int* pairs_out = (const int*)d_in[16];
  const int* pairs_act = (const int*)d_in[17];

  char* W = (char*)d_ws;
  auto alloc = [&](size_t bytes) { char* p = W; W += (bytes + 255) & ~255ull; return p; };
  unsigned short* WtTh = (unsigned short*)alloc((size_t)Dn * Dn * 2);
  unsigned short* WtTl = (unsigned short*)alloc((size_t)Dn * Dn * 2);
  unsigned short* WbTh = (unsigned short*)alloc((size_t)Dn * Dn * 2);
  unsigned short* WbTl = (unsigned short*)alloc((size_t)Dn * Dn * 2);
  unsigned short* WinTh = (unsigned short*)alloc((size_t)Dn * DIN * 2);
  unsigned short* WinTl = (unsigned short*)alloc((size_t)Dn * DIN * 2);
  unsigned short* WoTh = (unsigned short*)alloc((size_t)DOUT * Pn * 2);
  unsigned short* WoTl = (unsigned short*)alloc((size_t)DOUT * Pn * 2);
  unsigned short* WaTh = (unsigned short*)alloc((size_t)DOUT * Pn * 2);
  unsigned short* WaTl = (unsigned short*)alloc((size_t)DOUT * Pn * 2);
  unsigned short* xh = (unsigned short*)alloc((size_t)Bsz * DIN * 2);
  unsigned short* xl = (unsigned short*)alloc((size_t)Bsz * DIN * 2);
  unsigned short* fh = (unsigned short*)alloc((size_t)BD * 2);
  unsigned short* fl = (unsigned short*)alloc((size_t)BD * 2);
  float* qpart = (float*)alloc(8 * Dn * 4);
  float* base  = (float*)alloc((size_t)BD * 4);
  float* hist  = (float*)alloc((size_t)TT * BD * 4);
  unsigned short* zbh[2], *zbl[2];
  zbh[0] = (unsigned short*)alloc((size_t)BD * 2);
  zbl[0] = (unsigned short*)alloc((size_t)BD * 2);
  zbh[1] = (unsigned short*)alloc((size_t)BD * 2);
  zbl[1] = (unsigned short*)alloc((size_t)BD * 2);
  unsigned short* zT = (unsigned short*)alloc((size_t)TT * BD * 2);
  // S buffers alias the (dead-after-base-GEMM) WbT region: 4MB each
  unsigned short* Sh0 = WbTh;
  unsigned short* Sl0 = WbTh + (size_t)TT * Bsz * Pn;
  unsigned short* Sh1 = WbTl;
  unsigned short* Sl1 = WbTl + (size_t)TT * Bsz * Pn;

  float* outy = (float*)d_out;
  float* outq = outy + (size_t)Bsz * TT * DOUT;

  dim3 blk(256);
  dim3 blk512(512);
  // fused prep
  prep_kernel<<<dim3(2944), blk, 0, stream>>>(
      W_syn, W_in, W_out, W_act, x, z0,
      WtTh, WtTl, WbTh, WbTl, WinTh, WinTl, WoTh, WoTl, WaTh, WaTl,
      xh, xl, qpart);
  // feats = x @ W_in + b_in (split output)
  mfma_gemm<0><<<dim3(256), blk512, 0, stream>>>(xh, xl, WinTh, WinTl, b_in, nullptr, fh, fl,
                                                 Bsz, Dn, DIN, 8, 32);
  // base = feats @ W_syn_bot + b_syn
  mfma_gemm<1><<<dim3(256), blk512, 0, stream>>>(fh, fl, WbTh, WbTl, b_syn, base, nullptr, nullptr,
                                                 Bsz, Dn, Dn, 8, 32);
  // tick 0 (q-reduce folded)
  tick0_kernel<<<dim3(512), blk, 0, stream>>>(base, qpart, hist, w1, b1, w2, b2,
                                              zbh[0], zbl[0], zT);
  // ticks 1..7
  for (int tau = 1; tau < TT; ++tau) {
    const unsigned short* zih = zbh[(tau + 1) & 1];
    const unsigned short* zil = zbl[(tau + 1) & 1];
    unsigned short* zoh = zbh[tau & 1];
    unsigned short* zol = zbl[tau & 1];
    float* ho = hist + (size_t)tau * BD;
    unsigned short* zTo = zT + (size_t)tau * BD;
    switch (tau) {
      case 1: tick_mfma<1><<<dim3(256), blk512, 0, stream>>>(zih, zil, WtTh, WtTl, base, hist, ho, w1, b1, w2, b2, zoh, zol, zTo); break;
      case 2: tick_mfma<2><<<dim3(256), blk512, 0, stream>>>(zih, zil, WtTh, WtTl, base, hist, ho, w1, b1, w2, b2, zoh, zol, zTo); break;
      case 3: tick_mfma<3><<<dim3(256), blk512, 0, stream>>>(zih, zil, WtTh, WtTl, base, hist, ho, w1, b1, w2, b2, zoh, zol, zTo); break;
      case 4: tick_mfma<4><<<dim3(256), blk512, 0, stream>>>(zih, zil, WtTh, WtTl, base, hist, ho, w1, b1, w2, b2, zoh, zol, zTo); break;
      case 5: tick_mfma<5><<<dim3(256), blk512, 0, stream>>>(zih, zil, WtTh, WtTl, base, hist, ho, w1, b1, w2, b2, zoh, zol, zTo); break;
      case 6: tick_mfma<6><<<dim3(256), blk512, 0, stream>>>(zih, zil, WtTh, WtTl, base, hist, ho, w1, b1, w2, b2, zoh, zol, zTo); break;
      case 7: tick_mfma<7><<<dim3(256), blk512, 0, stream>>>(zih, zil, WtTh, WtTl, base, hist, ho, w1, b1, w2, b2, zoh, zol, zTo); break;
    }
  }
  // batched sync for both sets (bb split across blockIdx.z)
  sync_kernel<<<dim3(Pn / 8, 2, 2), dim3(512), 0, stream>>>(zT, pairs_out, pairs_act,
                                                            decay_out, decay_act,
                                                            Sh0, Sl0, Sh1, Sl1);
  // both output GEMMs in one launch; 4 M-tiles per block
  out_gemm<<<dim3(128, 2), blk512, 0, stream>>>(Sh0, Sl0, Sh1, Sl1,
                                                WoTh, WoTl, WaTh, WaTl,
                                                b_out, b_act, outy, outq);
}